// Round 7
// baseline (492.613 us; speedup 1.0000x reference)
//
#include <hip/hip_runtime.h>
#include <math.h>

typedef unsigned short ushort_t;
typedef __attribute__((ext_vector_type(8))) short short8;
typedef __attribute__((ext_vector_type(4))) float f32x4;

// Problem constants (fixed by setup_inputs)
#define NN    20000
#define DEG   16
constexpr int MAXL2 = 1 + DEG;            // 17
constexpr int MAXL1 = MAXL2 + MAXL2*DEG;  // 289
constexpr int L0PAD = 73 * 64;            // 4672 edge rows (padded MFMA tiles)
constexpr int GRID  = 256;                // persistent blocks; <=2/CU capacity -> co-resident

__device__ __forceinline__ ushort_t f2bf(float f) {
    unsigned u = __float_as_uint(f);
    return (ushort_t)((u + 0x7FFFu + ((u >> 16) & 1u)) >> 16);   // RTN-even
}
__device__ __forceinline__ int ldacq(int* p) { return atomicAdd(p, 0); }

struct WS {
    int* bars;                 // one-shot barrier counters (memset 0 by host)
    float *lgc0, *lgc1, *lgc2; // logits: lgc0 edge-indexed [L0PAD]
    float *C0, *C1, *C2;       // split-K accumulators (memset 0)
    int *inv1, *inv2, *list1, *list2, *list3, *cnts;
    ushort_t *Xg, *awT;
    float *hN0c, *h1c, *hN1c, *h2c, *hN2c;
};

// ---------------- fp32 tile GEMM (64x64, BK=32, register-prefetch) ----------------
// omode 0: C += acc (atomic, split-K OK). omode 1: lgc[r] += sum relu(acc)*aq (NO split-K).
__device__ void dev_mm(char* smem, int t,
                       const float* A1, const float* A2, const int* list, const int* inv,
                       const float* B, const float* aq, float* C, int rcnt,
                       int amode, int omode, int K1, int K2, int NC,
                       int row0, int col0, int kbeg, int kend) {
    float* As = (float*)smem;              // [32][68]
    float* Bs = As + 32 * 68;              // [32][64]
    float* rowsum = (float*)(smem + 16896);
    __syncthreads();

    int ty = t >> 4, tx = t & 15;
    int lr = t >> 2, kaoff = (t & 3) * 4;
    int grow = row0 + lr;
    bool rowValid = grow < rcnt;
    const float* rp1 = A1;
    const float* rp2 = A2;
    if (rowValid) {
        int hrow;
        if (amode == 0) hrow = grow;
        else { int node = list[grow]; hrow = (amode == 2) ? inv[node] : node; }
        rp1 = A1 + (size_t)hrow * K1;
        rp2 = A2 + (size_t)grow * K2;
    }
    const float* Bp = B + col0;
    int bidx0 = t, bidx1 = t + 256;

    auto loadA = [&](int k) -> float4 {
        if (!rowValid) return make_float4(0.f, 0.f, 0.f, 0.f);
        const float* src = (k < K1) ? (rp1 + k) : (rp2 + (k - K1));
        return *(const float4*)src;
    };
    auto loadB = [&](int idx, int k0) -> float4 {
        int row = idx >> 4, c4 = (idx & 15) * 4;
        return *(const float4*)(Bp + (size_t)(k0 + row) * NC + c4);
    };

    float4 pa0 = loadA(kbeg + kaoff);
    float4 pa1 = loadA(kbeg + kaoff + 16);
    float4 pb0 = loadB(bidx0, kbeg);
    float4 pb1 = loadB(bidx1, kbeg);

    float acc[4][4] = {};
    for (int k0 = kbeg; k0 < kend; k0 += 32) {
        As[(kaoff + 0) * 68 + lr] = pa0.x; As[(kaoff + 1) * 68 + lr] = pa0.y;
        As[(kaoff + 2) * 68 + lr] = pa0.z; As[(kaoff + 3) * 68 + lr] = pa0.w;
        As[(kaoff + 16) * 68 + lr] = pa1.x; As[(kaoff + 17) * 68 + lr] = pa1.y;
        As[(kaoff + 18) * 68 + lr] = pa1.z; As[(kaoff + 19) * 68 + lr] = pa1.w;
        *(float4*)&Bs[(bidx0 >> 4) * 64 + (bidx0 & 15) * 4] = pb0;
        *(float4*)&Bs[(bidx1 >> 4) * 64 + (bidx1 & 15) * 4] = pb1;
        __syncthreads();
        if (k0 + 32 < kend) {
            pa0 = loadA(k0 + 32 + kaoff);
            pa1 = loadA(k0 + 32 + kaoff + 16);
            pb0 = loadB(bidx0, k0 + 32);
            pb1 = loadB(bidx1, k0 + 32);
        }
#pragma unroll
        for (int kk = 0; kk < 32; kk++) {
            float4 a4 = *(const float4*)&As[kk * 68 + ty * 4];
            float4 b4 = *(const float4*)&Bs[kk * 64 + tx * 4];
            float a[4] = {a4.x, a4.y, a4.z, a4.w};
            float b[4] = {b4.x, b4.y, b4.z, b4.w};
#pragma unroll
            for (int i = 0; i < 4; i++)
#pragma unroll
                for (int j = 0; j < 4; j++) acc[i][j] += a[i] * b[j];
        }
        __syncthreads();
    }

    if (omode == 0) {
#pragma unroll
        for (int i = 0; i < 4; i++) {
            int r = row0 + ty * 4 + i;
            if (r < rcnt) {
                float* Crow = C + (size_t)r * NC + col0 + tx * 4;
#pragma unroll
                for (int j = 0; j < 4; j++) atomicAdd(&Crow[j], acc[i][j]);
            }
        }
    } else {
        if (t < 64) rowsum[t] = 0.f;
        __syncthreads();
        float aqv[4];
#pragma unroll
        for (int j = 0; j < 4; j++) aqv[j] = aq[col0 + tx * 4 + j];
#pragma unroll
        for (int i = 0; i < 4; i++) {
            float s = 0.f;
#pragma unroll
            for (int j = 0; j < 4; j++) {
                float v = acc[i][j];
                v = v > 0.f ? v : 0.f;
                s += v * aqv[j];
            }
            atomicAdd(&rowsum[ty * 4 + i], s);
        }
        __syncthreads();
        if (t < 64) {
            int r = row0 + t;
            if (r < rcnt) atomicAdd(&C[r], rowsum[t]);
        }
    }
}

// ---------------- bf16 MFMA logits tile (64x64, K-step 32) ----------------
__device__ void dev_logits_mfma(char* smem, int t,
                                const ushort_t* Xg, const ushort_t* WT,
                                const float* aq, float* lgc,
                                int row0, int col0, int K) {
    short* As = (short*)smem;          // [64][40]
    short* Bs = As + 64 * 40;
    __syncthreads();
    int w = t >> 6, lane = t & 63;
    int sr = t >> 2, sk = (t & 3) * 8;
    const ushort_t* ap = Xg + (size_t)(row0 + sr) * K + sk;
    const ushort_t* bp = WT + (size_t)(col0 + sr) * K + sk;
    int fm = lane & 15, fq = lane >> 4;
    const short* arow = As + (w * 16 + fm) * 40 + fq * 8;
    const short* brow = Bs + fm * 40 + fq * 8;

    f32x4 acc0 = {0.f,0.f,0.f,0.f}, acc1 = {0.f,0.f,0.f,0.f};
    f32x4 acc2 = {0.f,0.f,0.f,0.f}, acc3 = {0.f,0.f,0.f,0.f};

    short8 pa = *(const short8*)(ap);
    short8 pb = *(const short8*)(bp);
    for (int k0 = 0; k0 < K; k0 += 32) {
        *(short8*)(As + sr * 40 + sk) = pa;
        *(short8*)(Bs + sr * 40 + sk) = pb;
        __syncthreads();
        if (k0 + 32 < K) {
            pa = *(const short8*)(ap + k0 + 32);
            pb = *(const short8*)(bp + k0 + 32);
        }
        short8 af = *(const short8*)arow;
        short8 b0 = *(const short8*)(brow);
        short8 b1 = *(const short8*)(brow + 16 * 40);
        short8 b2 = *(const short8*)(brow + 32 * 40);
        short8 b3 = *(const short8*)(brow + 48 * 40);
        acc0 = __builtin_amdgcn_mfma_f32_16x16x32_bf16(af, b0, acc0, 0, 0, 0);
        acc1 = __builtin_amdgcn_mfma_f32_16x16x32_bf16(af, b1, acc1, 0, 0, 0);
        acc2 = __builtin_amdgcn_mfma_f32_16x16x32_bf16(af, b2, acc2, 0, 0, 0);
        acc3 = __builtin_amdgcn_mfma_f32_16x16x32_bf16(af, b3, acc3, 0, 0, 0);
        __syncthreads();
    }
    float aqv0 = aq[col0 + fm], aqv1 = aq[col0 + 16 + fm];
    float aqv2 = aq[col0 + 32 + fm], aqv3 = aq[col0 + 48 + fm];
#pragma unroll
    for (int r = 0; r < 4; r++) {
        float v = fmaxf(acc0[r], 0.f) * aqv0 + fmaxf(acc1[r], 0.f) * aqv1
                + fmaxf(acc2[r], 0.f) * aqv2 + fmaxf(acc3[r], 0.f) * aqv3;
#pragma unroll
        for (int off = 1; off < 16; off <<= 1) v += __shfl_xor(v, off);
        if (fm == 0) atomicAdd(&lgc[row0 + w * 16 + fq * 4 + r], v);
    }
}

// ---------------- softmax-aggregate over 16 senders ----------------
__device__ void dev_agg(int t, const int* senders_row, const int* inv,
                        const float* lgc, int edgeBase,
                        const float* Hsrc, int din, float* outp,
                        int* s_row, float* s_w, float* s_scale) {
    __syncthreads();
    if (t < DEG) {
        int s = senders_row[t];
        int rr = inv ? inv[s] : s;
        s_row[t] = rr;
        s_w[t] = (edgeBase >= 0) ? lgc[edgeBase + t] : lgc[rr];
    }
    __syncthreads();
    if (t == 0) {
        float m = -1e30f;
        for (int k = 0; k < DEG; k++) m = fmaxf(m, s_w[k]);
        float d = 0.f;
        for (int k = 0; k < DEG; k++) { float v = expf(s_w[k] - m); s_w[k] = v; d += v; }
        *s_scale = 1.f / d;
    }
    __syncthreads();
    float sc = *s_scale;
    for (int c = t; c < din; c += 256) {
        float a = 0.f;
#pragma unroll
        for (int k = 0; k < DEG; k++) a += s_w[k] * Hsrc[(size_t)s_row[k] * din + c];
        outp[c] = a * sc;
    }
}

// ---------------- the persistent mega-kernel ----------------
__global__ __launch_bounds__(256, 2)
void k_mega(const float* __restrict__ X, const int* __restrict__ senders,
            const float* lw0, const float* lb0, const float* aw0, const float* aq0,
            const float* lw1, const float* lb1, const float* aw1, const float* aq1,
            const float* lw2, const float* lb2, const float* aw2, const float* aq2,
            const float* ow, const float* ob, float* out, WS w) {
    __shared__ char smem[17408];
    __shared__ int   s_row[DEG];
    __shared__ float s_w[DEG];
    __shared__ float s_scale;
    __shared__ int   fcnt;
    int t = threadIdx.x, bid = blockIdx.x;

    auto gsync = [&](int idx) {
        __syncthreads();
        if (t == 0) {
            __threadfence();
            atomicAdd(&w.bars[idx], 1);
            while (atomicAdd(&w.bars[idx], 0) < GRID) __builtin_amdgcn_s_sleep(2);
            __threadfence();
        }
        __syncthreads();
    };

    // ---- S0: block0 = frontier (levels 2,1); others = aw0 transpose->bf16 ----
    if (bid == 0) {
        unsigned* bm = (unsigned*)smem;  // 625 words
        for (int i = t; i < 625; i += 256) bm[i] = 0u;
        if (t == 0) fcnt = 0;
        __syncthreads();
        if (t < 17) {
            int node = (t < 16) ? senders[14 * DEG + t] : 14;
            unsigned bit = 1u << (node & 31);
            if (!(atomicOr(&bm[node >> 5], bit) & bit)) {
                int p = atomicAdd(&fcnt, 1); w.list2[p] = node; w.inv2[node] = p;
            }
        }
        __syncthreads();
        int c2 = fcnt;
        __syncthreads();
        for (int i = t; i < 625; i += 256) bm[i] = 0u;
        if (t == 0) { w.cnts[2] = c2; fcnt = 0; }
        __syncthreads();
        for (int i = t; i < c2 * 17; i += 256) {
            int r = i / 17, k = i - 17 * r;
            int node = (k < 16) ? senders[w.list2[r] * DEG + k] : w.list2[r];
            unsigned bit = 1u << (node & 31);
            if (!(atomicOr(&bm[node >> 5], bit) & bit)) {
                int p = atomicAdd(&fcnt, 1); w.list1[p] = node; w.inv1[node] = p;
            }
        }
        __syncthreads();
        if (t == 0) { w.cnts[1] = fcnt; w.cnts[3] = 1; w.list3[0] = 14; }
    } else {
        float* tile = (float*)smem;  // [32][33]
        for (int b = bid - 1; b < 512; b += GRID - 1) {
            __syncthreads();
            int bx = b & 15, by = b >> 4;
            int i0 = t >> 3, j0 = (t & 7) * 4;
            float4 v = *(const float4*)(aw0 + (size_t)(by * 32 + i0) * 512 + bx * 32 + j0);
            tile[i0 * 33 + j0] = v.x; tile[i0 * 33 + j0 + 1] = v.y;
            tile[i0 * 33 + j0 + 2] = v.z; tile[i0 * 33 + j0 + 3] = v.w;
            __syncthreads();
            ushort_t* p = w.awT + (size_t)(bx * 32 + i0) * 1024 + by * 32 + j0;
            p[0] = f2bf(tile[(j0 + 0) * 33 + i0]); p[1] = f2bf(tile[(j0 + 1) * 33 + i0]);
            p[2] = f2bf(tile[(j0 + 2) * 33 + i0]); p[3] = f2bf(tile[(j0 + 3) * 33 + i0]);
        }
    }
    gsync(0);

    int rc1 = ldacq(&w.cnts[1]);
    int rc2 = ldacq(&w.cnts[2]);
    int ne = rc1 * DEG;

    // ---- S1: gather X[sender-of-edge] -> bf16 Xg (edge-indexed, zero-padded) ----
    for (int e = bid; e < L0PAD; e += GRID) {
        unsigned lo = 0, hi = 0;
        if (e < ne) {
            int node = senders[w.list1[e >> 4] * DEG + (e & 15)];
            float4 v = *(const float4*)(X + (size_t)node * 1024 + t * 4);
            lo = (unsigned)f2bf(v.x) | ((unsigned)f2bf(v.y) << 16);
            hi = (unsigned)f2bf(v.z) | ((unsigned)f2bf(v.w) << 16);
        }
        *(uint2*)(w.Xg + (size_t)e * 1024 + t * 4) = make_uint2(lo, hi);
    }
    gsync(1);

    // ---- S2: logits0 MFMA (edge rows x aw0), 73x8 tiles ----
    for (int task = bid; task < 73 * 8; task += GRID) {
        int xr = task % 73, yc = task / 73;
        dev_logits_mfma(smem, t, w.Xg, w.awT, aq0, w.lgc0, xr * 64, yc * 64, 1024);
    }
    gsync(2);

    // ---- S3: agg layer0 -> hN0c (din=1024, Hsrc=X raw) ----
    for (int r = bid; r < rc1; r += GRID)
        dev_agg(t, senders + (size_t)w.list1[r] * DEG, nullptr, w.lgc0, r * DEG,
                X, 1024, w.hN0c + (size_t)r * 1024, s_row, s_w, &s_scale);
    gsync(3);

    // ---- S4: h1 GEMM split-K8: C0 += concat(X[list1],hN0c) @ lw0 ----
    for (int task = bid; task < 5 * 8 * 8; task += GRID) {
        int z = task / 40, rem = task % 40, x = rem % 5, y = rem / 5;
        if (x * 64 < rc1)
            dev_mm(smem, t, X, w.hN0c, w.list1, nullptr, lw0, aq0, w.C0, rc1,
                   1, 0, 1024, 1024, 512, x * 64, y * 64, z * 256, z * 256 + 256);
    }
    gsync(4);

    // ---- S5: bias+relu -> h1c ----
    for (int i = bid * 256 + t; i < rc1 * 512; i += GRID * 256) {
        float v = w.C0[i] + lb0[i & 511];
        w.h1c[i] = v > 0.f ? v : 0.f;
    }
    gsync(5);

    // ---- S6: logits1 (fp32, fused relu*aq, full-K) ----
    for (int task = bid; task < 5 * 4; task += GRID) {
        int x = task % 5, y = task / 5;
        if (x * 64 < rc1)
            dev_mm(smem, t, w.h1c, w.h1c, nullptr, nullptr, aw1, aq1, w.lgc1, rc1,
                   0, 1, 512, 0, 256, x * 64, y * 64, 0, 512);
    }
    gsync(6);

    // ---- S7: agg layer1 -> hN1c (din=512) ----
    for (int r = bid; r < rc2; r += GRID)
        dev_agg(t, senders + (size_t)w.list2[r] * DEG, w.inv1, w.lgc1, -1,
                w.h1c, 512, w.hN1c + (size_t)r * 512, s_row, s_w, &s_scale);
    gsync(7);

    // ---- S8: h2 GEMM split-K8 ----
    for (int task = bid; task < 4 * 8; task += GRID) {
        int y = task & 3, z = task >> 2;
        dev_mm(smem, t, w.h1c, w.hN1c, w.list2, w.inv1, lw1, aq1, w.C1, rc2,
               2, 0, 512, 512, 256, 0, y * 64, z * 128, z * 128 + 128);
    }
    gsync(8);

    // ---- S9: bias+relu -> h2c ----
    for (int i = bid * 256 + t; i < rc2 * 256; i += GRID * 256) {
        float v = w.C1[i] + lb1[i & 255];
        w.h2c[i] = v > 0.f ? v : 0.f;
    }
    gsync(9);

    // ---- S10: logits2 ----
    for (int task = bid; task < 2; task += GRID)
        dev_mm(smem, t, w.h2c, w.h2c, nullptr, nullptr, aw2, aq2, w.lgc2, rc2,
               0, 1, 256, 0, 128, 0, task * 64, 0, 256);
    gsync(10);

    // ---- S11: agg layer2 (node 14 only) -> hN2c ----
    if (bid == 0)
        dev_agg(t, senders + 14 * DEG, w.inv2, w.lgc2, -1,
                w.h2c, 256, w.hN2c, s_row, s_w, &s_scale);
    gsync(11);

    // ---- S12: h3 GEMM split-K4 -> C2 ----
    for (int task = bid; task < 2 * 4; task += GRID) {
        int y = task & 1, z = task >> 1;
        dev_mm(smem, t, w.h2c, w.hN2c, w.list3, w.inv2, lw2, aq2, w.C2, 1,
               2, 0, 256, 256, 128, 0, y * 64, z * 128, z * 128 + 128);
    }
    gsync(12);

    // ---- S13: out = relu(C2+lb2) @ ow + ob ----
    if (bid == 0) {
        float* h3s = (float*)smem;
        float* part = h3s + 128;
        if (t < 128) { float v = w.C2[t] + lb2[t]; h3s[t] = v > 0.f ? v : 0.f; }
        __syncthreads();
        int j = t & 127, s = t >> 7;   // 2 k-slices of 64
        float a = 0.f;
        for (int k = s * 64; k < s * 64 + 64; k++) a += h3s[k] * ow[(size_t)k * 128 + j];
        part[s * 128 + j] = a;
        __syncthreads();
        if (t < 128) out[t] = ob[t] + part[t] + part[128 + t];
    }
}

// ---------------- launch ----------------
extern "C" void kernel_launch(void* const* d_in, const int* in_sizes, int n_in,
                              void* d_out, int out_size, void* d_ws, size_t ws_size,
                              hipStream_t stream) {
    const float* X       = (const float*)d_in[0];
    const int*   senders = (const int*)d_in[1];
    const float* lw0 = (const float*)d_in[3];
    const float* lb0 = (const float*)d_in[4];
    const float* aw0 = (const float*)d_in[5];
    const float* aq0 = (const float*)d_in[6];
    const float* lw1 = (const float*)d_in[7];
    const float* lb1 = (const float*)d_in[8];
    const float* aw1 = (const float*)d_in[9];
    const float* aq1 = (const float*)d_in[10];
    const float* lw2 = (const float*)d_in[11];
    const float* lb2 = (const float*)d_in[12];
    const float* aw2 = (const float*)d_in[13];
    const float* aq2 = (const float*)d_in[14];
    const float* owp = (const float*)d_in[15];
    const float* obp = (const float*)d_in[16];
    float* out = (float*)d_out;

    char* ws = (char*)d_ws;
    size_t off = 0;
    auto alloc = [&](size_t nbytes) -> void* {
        void* p = ws + off;
        off += (nbytes + 255) & ~(size_t)255;
        return p;
    };
    WS w;
    // ---- zero region (single hipMemsetAsync covers barriers + accumulators) ----
    w.bars = (int*)alloc(64 * 4);
    w.lgc0 = (float*)alloc(L0PAD * 4);
    w.lgc1 = (float*)alloc(MAXL1 * 4);
    w.lgc2 = (float*)alloc(MAXL2 * 4);
    w.C0   = (float*)alloc((size_t)MAXL1 * 512 * 4);
    w.C1   = (float*)alloc((size_t)MAXL2 * 256 * 4);
    w.C2   = (float*)alloc(128 * 4);
    size_t zero_end = off;
    // ---- rest ----
    w.inv1  = (int*)alloc(NN * 4);
    w.inv2  = (int*)alloc(NN * 4);
    w.list1 = (int*)alloc(MAXL1 * 4);
    w.list2 = (int*)alloc(MAXL2 * 4);
    w.list3 = (int*)alloc(4);
    w.cnts  = (int*)alloc(16);
    w.Xg    = (ushort_t*)alloc((size_t)L0PAD * 1024 * 2);
    w.awT   = (ushort_t*)alloc((size_t)512 * 1024 * 2);
    w.hN0c  = (float*)alloc((size_t)MAXL1 * 1024 * 4);
    w.h1c   = (float*)alloc((size_t)MAXL1 * 512 * 4);
    w.hN1c  = (float*)alloc((size_t)MAXL2 * 512 * 4);
    w.h2c   = (float*)alloc((size_t)MAXL2 * 256 * 4);
    w.hN2c  = (float*)alloc(256 * 4);
    (void)in_sizes; (void)n_in; (void)out_size; (void)ws_size;

    hipMemsetAsync(ws, 0, zero_end, stream);
    hipLaunchKernelGGL(k_mega, dim3(GRID), dim3(256), 0, stream,
                       X, senders, lw0, lb0, aw0, aq0, lw1, lb1, aw1, aq1,
                       lw2, lb2, aw2, aq2, owp, obp, out, w);
}

// Round 8
// 471.124 us; speedup vs baseline: 1.0456x; 1.0456x over previous
//
#include <hip/hip_runtime.h>
#include <math.h>

typedef unsigned short ushort_t;
typedef __attribute__((ext_vector_type(8))) short short8;
typedef __attribute__((ext_vector_type(4))) float f32x4;

// Problem constants (fixed by setup_inputs)
#define NN    20000
#define DEG   16
constexpr int MAXL2 = 1 + DEG;            // 17
constexpr int MAXL1 = MAXL2 + MAXL2*DEG;  // 289
constexpr int L0PAD = 73 * 64;            // 4672 edge rows (padded MFMA tiles)
constexpr int GRID  = 256;                // persistent blocks; 1/CU -> co-resident

__device__ __forceinline__ ushort_t f2bf(float f) {
    unsigned u = __float_as_uint(f);
    return (ushort_t)((u + 0x7FFFu + ((u >> 16) & 1u)) >> 16);   // RTN-even
}
__device__ __forceinline__ int ld_agent(int* p) {
    return __hip_atomic_load(p, __ATOMIC_RELAXED, __HIP_MEMORY_SCOPE_AGENT);
}

struct WS {
    int* bars;                 // one-shot barrier counters (memset 0 by host)
    float *lgc0, *lgc1, *lgc2; // logits: lgc0 edge-indexed [L0PAD]
    float *C0, *C1, *C2;       // split-K accumulators (memset 0); consumers apply bias+relu
    int *inv1, *inv2, *list1, *list2, *list3, *cnts;
    ushort_t *Xg, *awT;
    float *hN0c, *hN1c, *hN2c;
};

// ---------------- fp32 tile GEMM (64x64, BK=32, register-prefetch) ----------------
// A1 rows get optional fused relu(x+abias) (for reading raw split-K accumulators).
// omode 0: C += acc (atomic, split-K OK). omode 1: lgc[r] += sum relu(acc)*aq (NO split-K).
__device__ void dev_mm(char* smem, int t,
                       const float* A1, const float* A2, const int* list, const int* inv,
                       const float* B, const float* aq, const float* abias,
                       float* C, int rcnt,
                       int amode, int omode, int K1, int K2, int NC,
                       int row0, int col0, int kbeg, int kend) {
    float* As = (float*)smem;              // [32][68]
    float* Bs = As + 32 * 68;              // [32][64]
    float* rowsum = (float*)(smem + 16896);
    __syncthreads();

    int ty = t >> 4, tx = t & 15;
    int lr = t >> 2, kaoff = (t & 3) * 4;
    int grow = row0 + lr;
    bool rowValid = grow < rcnt;
    const float* rp1 = A1;
    const float* rp2 = A2;
    if (rowValid) {
        int hrow;
        if (amode == 0) hrow = grow;
        else { int node = list[grow]; hrow = (amode == 2) ? inv[node] : node; }
        rp1 = A1 + (size_t)hrow * K1;
        rp2 = A2 + (size_t)grow * K2;
    }
    const float* Bp = B + col0;
    int bidx0 = t, bidx1 = t + 256;

    auto loadA = [&](int k) -> float4 {
        if (!rowValid) return make_float4(0.f, 0.f, 0.f, 0.f);
        if (k < K1) {
            float4 v = *(const float4*)(rp1 + k);
            if (abias) {
                const float4 b = *(const float4*)(abias + k);
                v.x = fmaxf(v.x + b.x, 0.f); v.y = fmaxf(v.y + b.y, 0.f);
                v.z = fmaxf(v.z + b.z, 0.f); v.w = fmaxf(v.w + b.w, 0.f);
            }
            return v;
        }
        return *(const float4*)(rp2 + (k - K1));
    };
    auto loadB = [&](int idx, int k0) -> float4 {
        int row = idx >> 4, c4 = (idx & 15) * 4;
        return *(const float4*)(Bp + (size_t)(k0 + row) * NC + c4);
    };

    float4 pa0 = loadA(kbeg + kaoff);
    float4 pa1 = loadA(kbeg + kaoff + 16);
    float4 pb0 = loadB(bidx0, kbeg);
    float4 pb1 = loadB(bidx1, kbeg);

    float acc[4][4] = {};
    for (int k0 = kbeg; k0 < kend; k0 += 32) {
        As[(kaoff + 0) * 68 + lr] = pa0.x; As[(kaoff + 1) * 68 + lr] = pa0.y;
        As[(kaoff + 2) * 68 + lr] = pa0.z; As[(kaoff + 3) * 68 + lr] = pa0.w;
        As[(kaoff + 16) * 68 + lr] = pa1.x; As[(kaoff + 17) * 68 + lr] = pa1.y;
        As[(kaoff + 18) * 68 + lr] = pa1.z; As[(kaoff + 19) * 68 + lr] = pa1.w;
        *(float4*)&Bs[(bidx0 >> 4) * 64 + (bidx0 & 15) * 4] = pb0;
        *(float4*)&Bs[(bidx1 >> 4) * 64 + (bidx1 & 15) * 4] = pb1;
        __syncthreads();
        if (k0 + 32 < kend) {
            pa0 = loadA(k0 + 32 + kaoff);
            pa1 = loadA(k0 + 32 + kaoff + 16);
            pb0 = loadB(bidx0, k0 + 32);
            pb1 = loadB(bidx1, k0 + 32);
        }
#pragma unroll
        for (int kk = 0; kk < 32; kk++) {
            float4 a4 = *(const float4*)&As[kk * 68 + ty * 4];
            float4 b4 = *(const float4*)&Bs[kk * 64 + tx * 4];
            float a[4] = {a4.x, a4.y, a4.z, a4.w};
            float b[4] = {b4.x, b4.y, b4.z, b4.w};
#pragma unroll
            for (int i = 0; i < 4; i++)
#pragma unroll
                for (int j = 0; j < 4; j++) acc[i][j] += a[i] * b[j];
        }
        __syncthreads();
    }

    if (omode == 0) {
#pragma unroll
        for (int i = 0; i < 4; i++) {
            int r = row0 + ty * 4 + i;
            if (r < rcnt) {
                float* Crow = C + (size_t)r * NC + col0 + tx * 4;
#pragma unroll
                for (int j = 0; j < 4; j++) atomicAdd(&Crow[j], acc[i][j]);
            }
        }
    } else {
        if (t < 64) rowsum[t] = 0.f;
        __syncthreads();
        float aqv[4];
#pragma unroll
        for (int j = 0; j < 4; j++) aqv[j] = aq[col0 + tx * 4 + j];
#pragma unroll
        for (int i = 0; i < 4; i++) {
            float s = 0.f;
#pragma unroll
            for (int j = 0; j < 4; j++) {
                float v = acc[i][j];
                v = v > 0.f ? v : 0.f;
                s += v * aqv[j];
            }
            atomicAdd(&rowsum[ty * 4 + i], s);
        }
        __syncthreads();
        if (t < 64) {
            int r = row0 + t;
            if (r < rcnt) atomicAdd(&C[r], rowsum[t]);
        }
    }
}

// ---------------- bf16 MFMA logits tile (64x64, K-step 32) ----------------
__device__ void dev_logits_mfma(char* smem, int t,
                                const ushort_t* Xg, const ushort_t* WT,
                                const float* aq, float* lgc,
                                int row0, int col0, int K) {
    short* As = (short*)smem;          // [64][40]
    short* Bs = As + 64 * 40;
    __syncthreads();
    int w = t >> 6, lane = t & 63;
    int sr = t >> 2, sk = (t & 3) * 8;
    const ushort_t* ap = Xg + (size_t)(row0 + sr) * K + sk;
    const ushort_t* bp = WT + (size_t)(col0 + sr) * K + sk;
    int fm = lane & 15, fq = lane >> 4;
    const short* arow = As + (w * 16 + fm) * 40 + fq * 8;
    const short* brow = Bs + fm * 40 + fq * 8;

    f32x4 acc0 = {0.f,0.f,0.f,0.f}, acc1 = {0.f,0.f,0.f,0.f};
    f32x4 acc2 = {0.f,0.f,0.f,0.f}, acc3 = {0.f,0.f,0.f,0.f};

    short8 pa = *(const short8*)(ap);
    short8 pb = *(const short8*)(bp);
    for (int k0 = 0; k0 < K; k0 += 32) {
        *(short8*)(As + sr * 40 + sk) = pa;
        *(short8*)(Bs + sr * 40 + sk) = pb;
        __syncthreads();
        if (k0 + 32 < K) {
            pa = *(const short8*)(ap + k0 + 32);
            pb = *(const short8*)(bp + k0 + 32);
        }
        short8 af = *(const short8*)arow;
        short8 b0 = *(const short8*)(brow);
        short8 b1 = *(const short8*)(brow + 16 * 40);
        short8 b2 = *(const short8*)(brow + 32 * 40);
        short8 b3 = *(const short8*)(brow + 48 * 40);
        acc0 = __builtin_amdgcn_mfma_f32_16x16x32_bf16(af, b0, acc0, 0, 0, 0);
        acc1 = __builtin_amdgcn_mfma_f32_16x16x32_bf16(af, b1, acc1, 0, 0, 0);
        acc2 = __builtin_amdgcn_mfma_f32_16x16x32_bf16(af, b2, acc2, 0, 0, 0);
        acc3 = __builtin_amdgcn_mfma_f32_16x16x32_bf16(af, b3, acc3, 0, 0, 0);
        __syncthreads();
    }
    float aqv0 = aq[col0 + fm], aqv1 = aq[col0 + 16 + fm];
    float aqv2 = aq[col0 + 32 + fm], aqv3 = aq[col0 + 48 + fm];
#pragma unroll
    for (int r = 0; r < 4; r++) {
        float v = fmaxf(acc0[r], 0.f) * aqv0 + fmaxf(acc1[r], 0.f) * aqv1
                + fmaxf(acc2[r], 0.f) * aqv2 + fmaxf(acc3[r], 0.f) * aqv3;
#pragma unroll
        for (int off = 1; off < 16; off <<= 1) v += __shfl_xor(v, off);
        if (fm == 0) atomicAdd(&lgc[row0 + w * 16 + fq * 4 + r], v);
    }
}

// ---------------- softmax-aggregate over 16 senders (optional fused relu(H+hbias)) ----------------
__device__ void dev_agg(int t, const int* senders_row, const int* inv,
                        const float* lgc, int edgeBase,
                        const float* Hsrc, const float* hbias, int din, float* outp,
                        int* s_row, float* s_w, float* s_scale) {
    __syncthreads();
    if (t < DEG) {
        int s = senders_row[t];
        int rr = inv ? inv[s] : s;
        s_row[t] = rr;
        s_w[t] = (edgeBase >= 0) ? lgc[edgeBase + t] : lgc[rr];
    }
    __syncthreads();
    if (t == 0) {
        float m = -1e30f;
        for (int k = 0; k < DEG; k++) m = fmaxf(m, s_w[k]);
        float d = 0.f;
        for (int k = 0; k < DEG; k++) { float v = expf(s_w[k] - m); s_w[k] = v; d += v; }
        *s_scale = 1.f / d;
    }
    __syncthreads();
    float sc = *s_scale;
    for (int c = t; c < din; c += 256) {
        float bc = hbias ? hbias[c] : 0.f;
        float a = 0.f;
#pragma unroll
        for (int k = 0; k < DEG; k++) {
            float hv = Hsrc[(size_t)s_row[k] * din + c];
            if (hbias) hv = fmaxf(hv + bc, 0.f);
            a += s_w[k] * hv;
        }
        outp[c] = a * sc;
    }
}

// ---------------- the persistent mega-kernel ----------------
__global__ __launch_bounds__(256, 2)
void k_mega(const float* __restrict__ X, const int* __restrict__ senders,
            const float* lw0, const float* lb0, const float* aw0, const float* aq0,
            const float* lw1, const float* lb1, const float* aw1, const float* aq1,
            const float* lw2, const float* lb2, const float* aw2, const float* aq2,
            const float* ow, const float* ob, float* out, WS w) {
    __shared__ char smem[17408];
    __shared__ int   s_row[DEG];
    __shared__ float s_w[DEG];
    __shared__ float s_scale;
    __shared__ int   fcnt;
    int t = threadIdx.x, bid = blockIdx.x;

    // Barrier: arrive = one RMW; wait = agent-scope atomic LOAD poll (read-only,
    // served in parallel — the round-7 atomicAdd(p,0) RMW poll serialized at ~20us/barrier).
    auto gsync = [&](int idx) {
        __syncthreads();
        if (t == 0) {
            __threadfence();
            atomicAdd(&w.bars[idx], 1);
            while (ld_agent(&w.bars[idx]) < GRID) __builtin_amdgcn_s_sleep(8);
            __threadfence();
        }
        __syncthreads();
    };

    // ---- S0: block0 = frontier (levels 2,1); others = aw0 transpose->bf16 ----
    if (bid == 0) {
        unsigned* bm = (unsigned*)smem;  // 625 words
        for (int i = t; i < 625; i += 256) bm[i] = 0u;
        if (t == 0) fcnt = 0;
        __syncthreads();
        if (t < 17) {
            int node = (t < 16) ? senders[14 * DEG + t] : 14;
            unsigned bit = 1u << (node & 31);
            if (!(atomicOr(&bm[node >> 5], bit) & bit)) {
                int p = atomicAdd(&fcnt, 1); w.list2[p] = node; w.inv2[node] = p;
            }
        }
        __syncthreads();
        int c2 = fcnt;
        __syncthreads();
        for (int i = t; i < 625; i += 256) bm[i] = 0u;
        if (t == 0) { w.cnts[2] = c2; fcnt = 0; }
        __syncthreads();
        for (int i = t; i < c2 * 17; i += 256) {
            int r = i / 17, k = i - 17 * r;
            int node = (k < 16) ? senders[w.list2[r] * DEG + k] : w.list2[r];
            unsigned bit = 1u << (node & 31);
            if (!(atomicOr(&bm[node >> 5], bit) & bit)) {
                int p = atomicAdd(&fcnt, 1); w.list1[p] = node; w.inv1[node] = p;
            }
        }
        __syncthreads();
        if (t == 0) { w.cnts[1] = fcnt; w.cnts[3] = 1; w.list3[0] = 14; }
    } else {
        float* tile = (float*)smem;  // [32][33]
        for (int b = bid - 1; b < 512; b += GRID - 1) {
            __syncthreads();
            int bx = b & 15, by = b >> 4;
            int i0 = t >> 3, j0 = (t & 7) * 4;
            float4 v = *(const float4*)(aw0 + (size_t)(by * 32 + i0) * 512 + bx * 32 + j0);
            tile[i0 * 33 + j0] = v.x; tile[i0 * 33 + j0 + 1] = v.y;
            tile[i0 * 33 + j0 + 2] = v.z; tile[i0 * 33 + j0 + 3] = v.w;
            __syncthreads();
            ushort_t* p = w.awT + (size_t)(bx * 32 + i0) * 1024 + by * 32 + j0;
            p[0] = f2bf(tile[(j0 + 0) * 33 + i0]); p[1] = f2bf(tile[(j0 + 1) * 33 + i0]);
            p[2] = f2bf(tile[(j0 + 2) * 33 + i0]); p[3] = f2bf(tile[(j0 + 3) * 33 + i0]);
        }
    }
    gsync(0);

    int rc1 = ld_agent(&w.cnts[1]);
    int rc2 = ld_agent(&w.cnts[2]);
    int ne = rc1 * DEG;

    // ---- S1: gather X[sender-of-edge] -> bf16 Xg (edge-indexed, zero-padded) ----
    for (int e = bid; e < L0PAD; e += GRID) {
        unsigned lo = 0, hi = 0;
        if (e < ne) {
            int node = senders[w.list1[e >> 4] * DEG + (e & 15)];
            float4 v = *(const float4*)(X + (size_t)node * 1024 + t * 4);
            lo = (unsigned)f2bf(v.x) | ((unsigned)f2bf(v.y) << 16);
            hi = (unsigned)f2bf(v.z) | ((unsigned)f2bf(v.w) << 16);
        }
        *(uint2*)(w.Xg + (size_t)e * 1024 + t * 4) = make_uint2(lo, hi);
    }
    gsync(1);

    // ---- S2: logits0 MFMA (edge rows x aw0), 73x8 tiles ----
    for (int task = bid; task < 73 * 8; task += GRID) {
        int xr = task % 73, yc = task / 73;
        dev_logits_mfma(smem, t, w.Xg, w.awT, aq0, w.lgc0, xr * 64, yc * 64, 1024);
    }
    gsync(2);

    // ---- S3: agg layer0 -> hN0c (din=1024, Hsrc=X raw) ----
    for (int r = bid; r < rc1; r += GRID)
        dev_agg(t, senders + (size_t)w.list1[r] * DEG, nullptr, w.lgc0, r * DEG,
                X, nullptr, 1024, w.hN0c + (size_t)r * 1024, s_row, s_w, &s_scale);
    gsync(3);

    // ---- S4: h1 GEMM split-K8: C0 += concat(X[list1],hN0c) @ lw0 ----
    for (int task = bid; task < 5 * 8 * 8; task += GRID) {
        int z = task / 40, rem = task % 40, x = rem % 5, y = rem / 5;
        if (x * 64 < rc1)
            dev_mm(smem, t, X, w.hN0c, w.list1, nullptr, lw0, aq0, nullptr, w.C0, rc1,
                   1, 0, 1024, 1024, 512, x * 64, y * 64, z * 256, z * 256 + 256);
    }
    gsync(4);

    // ---- S5: logits1 (A = relu(C0+lb0) on the fly, fused relu*aq, full-K) ----
    for (int task = bid; task < 5 * 4; task += GRID) {
        int x = task % 5, y = task / 5;
        if (x * 64 < rc1)
            dev_mm(smem, t, w.C0, nullptr, nullptr, nullptr, aw1, aq1, lb0, w.lgc1, rc1,
                   0, 1, 512, 0, 256, x * 64, y * 64, 0, 512);
    }
    gsync(5);

    // ---- S6: agg layer1 -> hN1c (din=512, Hsrc = relu(C0+lb0)) ----
    for (int r = bid; r < rc2; r += GRID)
        dev_agg(t, senders + (size_t)w.list2[r] * DEG, w.inv1, w.lgc1, -1,
                w.C0, lb0, 512, w.hN1c + (size_t)r * 512, s_row, s_w, &s_scale);
    gsync(6);

    // ---- S7: h2 GEMM split-K8: C1 += concat(relu(C0+lb0)[inv1], hN1c) @ lw1 ----
    for (int task = bid; task < 4 * 8; task += GRID) {
        int y = task & 3, z = task >> 2;
        dev_mm(smem, t, w.C0, w.hN1c, w.list2, w.inv1, lw1, aq1, lb0, w.C1, rc2,
               2, 0, 512, 512, 256, 0, y * 64, z * 128, z * 128 + 128);
    }
    gsync(7);

    // ---- S8: logits2 (A = relu(C1+lb1)) ----
    for (int task = bid; task < 2; task += GRID)
        dev_mm(smem, t, w.C1, nullptr, nullptr, nullptr, aw2, aq2, lb1, w.lgc2, rc2,
               0, 1, 256, 0, 128, 0, task * 64, 0, 256);
    gsync(8);

    // ---- S9: agg layer2 (node 14 only) -> hN2c (Hsrc = relu(C1+lb1)) ----
    if (bid == 0)
        dev_agg(t, senders + 14 * DEG, w.inv2, w.lgc2, -1,
                w.C1, lb1, 256, w.hN2c, s_row, s_w, &s_scale);
    gsync(9);

    // ---- S10: h3 GEMM split-K4 -> C2 ----
    for (int task = bid; task < 2 * 4; task += GRID) {
        int y = task & 1, z = task >> 1;
        dev_mm(smem, t, w.C1, w.hN2c, w.list3, w.inv2, lw2, aq2, lb1, w.C2, 1,
               2, 0, 256, 256, 128, 0, y * 64, z * 128, z * 128 + 128);
    }
    gsync(10);

    // ---- S11: out = relu(C2+lb2) @ ow + ob ----
    if (bid == 0) {
        float* h3s = (float*)smem;
        float* part = h3s + 128;
        if (t < 128) { float v = w.C2[t] + lb2[t]; h3s[t] = v > 0.f ? v : 0.f; }
        __syncthreads();
        int j = t & 127, s = t >> 7;   // 2 k-slices of 64
        float a = 0.f;
        for (int k = s * 64; k < s * 64 + 64; k++) a += h3s[k] * ow[(size_t)k * 128 + j];
        part[s * 128 + j] = a;
        __syncthreads();
        if (t < 128) out[t] = ob[t] + part[t] + part[128 + t];
    }
}

// ---------------- launch ----------------
extern "C" void kernel_launch(void* const* d_in, const int* in_sizes, int n_in,
                              void* d_out, int out_size, void* d_ws, size_t ws_size,
                              hipStream_t stream) {
    const float* X       = (const float*)d_in[0];
    const int*   senders = (const int*)d_in[1];
    const float* lw0 = (const float*)d_in[3];
    const float* lb0 = (const float*)d_in[4];
    const float* aw0 = (const float*)d_in[5];
    const float* aq0 = (const float*)d_in[6];
    const float* lw1 = (const float*)d_in[7];
    const float* lb1 = (const float*)d_in[8];
    const float* aw1 = (const float*)d_in[9];
    const float* aq1 = (const float*)d_in[10];
    const float* lw2 = (const float*)d_in[11];
    const float* lb2 = (const float*)d_in[12];
    const float* aw2 = (const float*)d_in[13];
    const float* aq2 = (const float*)d_in[14];
    const float* owp = (const float*)d_in[15];
    const float* obp = (const float*)d_in[16];
    float* out = (float*)d_out;

    char* ws = (char*)d_ws;
    size_t off = 0;
    auto alloc = [&](size_t nbytes) -> void* {
        void* p = ws + off;
        off += (nbytes + 255) & ~(size_t)255;
        return p;
    };
    WS w;
    // ---- zero region (single hipMemsetAsync covers barriers + accumulators) ----
    w.bars = (int*)alloc(64 * 4);
    w.lgc0 = (float*)alloc(L0PAD * 4);
    w.lgc1 = (float*)alloc(MAXL1 * 4);
    w.lgc2 = (float*)alloc(MAXL2 * 4);
    w.C0   = (float*)alloc((size_t)MAXL1 * 512 * 4);
    w.C1   = (float*)alloc((size_t)MAXL2 * 256 * 4);
    w.C2   = (float*)alloc(128 * 4);
    size_t zero_end = off;
    // ---- rest ----
    w.inv1  = (int*)alloc(NN * 4);
    w.inv2  = (int*)alloc(NN * 4);
    w.list1 = (int*)alloc(MAXL1 * 4);
    w.list2 = (int*)alloc(MAXL2 * 4);
    w.list3 = (int*)alloc(4);
    w.cnts  = (int*)alloc(16);
    w.Xg    = (ushort_t*)alloc((size_t)L0PAD * 1024 * 2);
    w.awT   = (ushort_t*)alloc((size_t)512 * 1024 * 2);
    w.hN0c  = (float*)alloc((size_t)MAXL1 * 1024 * 4);
    w.hN1c  = (float*)alloc((size_t)MAXL2 * 512 * 4);
    w.hN2c  = (float*)alloc(256 * 4);
    (void)in_sizes; (void)n_in; (void)out_size; (void)ws_size;

    hipMemsetAsync(ws, 0, zero_end, stream);
    hipLaunchKernelGGL(k_mega, dim3(GRID), dim3(256), 0, stream,
                       X, senders, lw0, lb0, aw0, aq0, lw1, lb1, aw1, aq1,
                       lw2, lb2, aw2, aq2, owp, obp, out, w);
}

// Round 9
// 470.353 us; speedup vs baseline: 1.0473x; 1.0016x over previous
//
#include <hip/hip_runtime.h>
#include <math.h>

typedef unsigned short ushort_t;
typedef __attribute__((ext_vector_type(8))) short short8;
typedef __attribute__((ext_vector_type(4))) float f32x4;

// Problem constants (fixed by setup_inputs)
#define NN    20000
#define DEG   16
constexpr int MAXL2 = 1 + DEG;            // 17
constexpr int MAXL1 = MAXL2 + MAXL2*DEG;  // 289
constexpr int L0PAD = 73 * 64;            // 4672 edge rows (padded MFMA tiles)
constexpr int GRID  = 512;                // persistent blocks; 2/CU guaranteed by launch_bounds
constexpr int NGRP  = 16;                 // tree-barrier groups (32 blocks each)
constexpr int GSTR  = 16*16 + 16 + 16*16; // ints per stage: grp[16]x16, root x16, go[16]x16

__device__ __forceinline__ ushort_t f2bf(float f) {
    unsigned u = __float_as_uint(f);
    return (ushort_t)((u + 0x7FFFu + ((u >> 16) & 1u)) >> 16);   // RTN-even
}
__device__ __forceinline__ int ld_agent(int* p) {
    return __hip_atomic_load(p, __ATOMIC_RELAXED, __HIP_MEMORY_SCOPE_AGENT);
}

struct WS {
    int* bars;                 // tree-barrier counters/flags (memset 0 by host)
    float *lgc0, *lgc1, *lgc2; // logits: lgc0 edge-indexed [L0PAD]
    float *C0, *C1, *C2;       // split-K accumulators (memset 0); consumers apply bias+relu
    int *inv1, *inv2, *list1, *list2, *list3, *cnts;
    ushort_t *Xg, *awT;
    float *hN0c, *hN1c, *hN2c;
};

// ---------------- fp32 tile GEMM (64x64, BK=32, register-prefetch) ----------------
// A1 rows get optional fused relu(x+abias) (for reading raw split-K accumulators).
// omode 0: C += acc (atomic, split-K OK). omode 1: lgc[r] += sum relu(acc)*aq (NO split-K).
__device__ void dev_mm(char* smem, int t,
                       const float* A1, const float* A2, const int* list, const int* inv,
                       const float* B, const float* aq, const float* abias,
                       float* C, int rcnt,
                       int amode, int omode, int K1, int K2, int NC,
                       int row0, int col0, int kbeg, int kend) {
    float* As = (float*)smem;              // [32][68]
    float* Bs = As + 32 * 68;              // [32][64]
    float* rowsum = (float*)(smem + 16896);
    __syncthreads();

    int ty = t >> 4, tx = t & 15;
    int lr = t >> 2, kaoff = (t & 3) * 4;
    int grow = row0 + lr;
    bool rowValid = grow < rcnt;
    const float* rp1 = A1;
    const float* rp2 = A2;
    if (rowValid) {
        int hrow;
        if (amode == 0) hrow = grow;
        else { int node = list[grow]; hrow = (amode == 2) ? inv[node] : node; }
        rp1 = A1 + (size_t)hrow * K1;
        rp2 = A2 + (size_t)grow * K2;
    }
    const float* Bp = B + col0;
    int bidx0 = t, bidx1 = t + 256;

    auto loadA = [&](int k) -> float4 {
        if (!rowValid) return make_float4(0.f, 0.f, 0.f, 0.f);
        if (k < K1) {
            float4 v = *(const float4*)(rp1 + k);
            if (abias) {
                const float4 b = *(const float4*)(abias + k);
                v.x = fmaxf(v.x + b.x, 0.f); v.y = fmaxf(v.y + b.y, 0.f);
                v.z = fmaxf(v.z + b.z, 0.f); v.w = fmaxf(v.w + b.w, 0.f);
            }
            return v;
        }
        return *(const float4*)(rp2 + (k - K1));
    };
    auto loadB = [&](int idx, int k0) -> float4 {
        int row = idx >> 4, c4 = (idx & 15) * 4;
        return *(const float4*)(Bp + (size_t)(k0 + row) * NC + c4);
    };

    float4 pa0 = loadA(kbeg + kaoff);
    float4 pa1 = loadA(kbeg + kaoff + 16);
    float4 pb0 = loadB(bidx0, kbeg);
    float4 pb1 = loadB(bidx1, kbeg);

    float acc[4][4] = {};
    for (int k0 = kbeg; k0 < kend; k0 += 32) {
        As[(kaoff + 0) * 68 + lr] = pa0.x; As[(kaoff + 1) * 68 + lr] = pa0.y;
        As[(kaoff + 2) * 68 + lr] = pa0.z; As[(kaoff + 3) * 68 + lr] = pa0.w;
        As[(kaoff + 16) * 68 + lr] = pa1.x; As[(kaoff + 17) * 68 + lr] = pa1.y;
        As[(kaoff + 18) * 68 + lr] = pa1.z; As[(kaoff + 19) * 68 + lr] = pa1.w;
        *(float4*)&Bs[(bidx0 >> 4) * 64 + (bidx0 & 15) * 4] = pb0;
        *(float4*)&Bs[(bidx1 >> 4) * 64 + (bidx1 & 15) * 4] = pb1;
        __syncthreads();
        if (k0 + 32 < kend) {
            pa0 = loadA(k0 + 32 + kaoff);
            pa1 = loadA(k0 + 32 + kaoff + 16);
            pb0 = loadB(bidx0, k0 + 32);
            pb1 = loadB(bidx1, k0 + 32);
        }
#pragma unroll
        for (int kk = 0; kk < 32; kk++) {
            float4 a4 = *(const float4*)&As[kk * 68 + ty * 4];
            float4 b4 = *(const float4*)&Bs[kk * 64 + tx * 4];
            float a[4] = {a4.x, a4.y, a4.z, a4.w};
            float b[4] = {b4.x, b4.y, b4.z, b4.w};
#pragma unroll
            for (int i = 0; i < 4; i++)
#pragma unroll
                for (int j = 0; j < 4; j++) acc[i][j] += a[i] * b[j];
        }
        __syncthreads();
    }

    if (omode == 0) {
#pragma unroll
        for (int i = 0; i < 4; i++) {
            int r = row0 + ty * 4 + i;
            if (r < rcnt) {
                float* Crow = C + (size_t)r * NC + col0 + tx * 4;
#pragma unroll
                for (int j = 0; j < 4; j++) atomicAdd(&Crow[j], acc[i][j]);
            }
        }
    } else {
        if (t < 64) rowsum[t] = 0.f;
        __syncthreads();
        float aqv[4];
#pragma unroll
        for (int j = 0; j < 4; j++) aqv[j] = aq[col0 + tx * 4 + j];
#pragma unroll
        for (int i = 0; i < 4; i++) {
            float s = 0.f;
#pragma unroll
            for (int j = 0; j < 4; j++) {
                float v = acc[i][j];
                v = v > 0.f ? v : 0.f;
                s += v * aqv[j];
            }
            atomicAdd(&rowsum[ty * 4 + i], s);
        }
        __syncthreads();
        if (t < 64) {
            int r = row0 + t;
            if (r < rcnt) atomicAdd(&C[r], rowsum[t]);
        }
    }
}

// ---------------- bf16 MFMA logits tile (64x64, K-step 32) ----------------
__device__ void dev_logits_mfma(char* smem, int t,
                                const ushort_t* Xg, const ushort_t* WT,
                                const float* aq, float* lgc,
                                int row0, int col0, int K) {
    short* As = (short*)smem;          // [64][40]
    short* Bs = As + 64 * 40;
    __syncthreads();
    int w = t >> 6, lane = t & 63;
    int sr = t >> 2, sk = (t & 3) * 8;
    const ushort_t* ap = Xg + (size_t)(row0 + sr) * K + sk;
    const ushort_t* bp = WT + (size_t)(col0 + sr) * K + sk;
    int fm = lane & 15, fq = lane >> 4;
    const short* arow = As + (w * 16 + fm) * 40 + fq * 8;
    const short* brow = Bs + fm * 40 + fq * 8;

    f32x4 acc0 = {0.f,0.f,0.f,0.f}, acc1 = {0.f,0.f,0.f,0.f};
    f32x4 acc2 = {0.f,0.f,0.f,0.f}, acc3 = {0.f,0.f,0.f,0.f};

    short8 pa = *(const short8*)(ap);
    short8 pb = *(const short8*)(bp);
    for (int k0 = 0; k0 < K; k0 += 32) {
        *(short8*)(As + sr * 40 + sk) = pa;
        *(short8*)(Bs + sr * 40 + sk) = pb;
        __syncthreads();
        if (k0 + 32 < K) {
            pa = *(const short8*)(ap + k0 + 32);
            pb = *(const short8*)(bp + k0 + 32);
        }
        short8 af = *(const short8*)arow;
        short8 b0 = *(const short8*)(brow);
        short8 b1 = *(const short8*)(brow + 16 * 40);
        short8 b2 = *(const short8*)(brow + 32 * 40);
        short8 b3 = *(const short8*)(brow + 48 * 40);
        acc0 = __builtin_amdgcn_mfma_f32_16x16x32_bf16(af, b0, acc0, 0, 0, 0);
        acc1 = __builtin_amdgcn_mfma_f32_16x16x32_bf16(af, b1, acc1, 0, 0, 0);
        acc2 = __builtin_amdgcn_mfma_f32_16x16x32_bf16(af, b2, acc2, 0, 0, 0);
        acc3 = __builtin_amdgcn_mfma_f32_16x16x32_bf16(af, b3, acc3, 0, 0, 0);
        __syncthreads();
    }
    float aqv0 = aq[col0 + fm], aqv1 = aq[col0 + 16 + fm];
    float aqv2 = aq[col0 + 32 + fm], aqv3 = aq[col0 + 48 + fm];
#pragma unroll
    for (int r = 0; r < 4; r++) {
        float v = fmaxf(acc0[r], 0.f) * aqv0 + fmaxf(acc1[r], 0.f) * aqv1
                + fmaxf(acc2[r], 0.f) * aqv2 + fmaxf(acc3[r], 0.f) * aqv3;
#pragma unroll
        for (int off = 1; off < 16; off <<= 1) v += __shfl_xor(v, off);
        if (fm == 0) atomicAdd(&lgc[row0 + w * 16 + fq * 4 + r], v);
    }
}

// ---------------- softmax-aggregate over 16 senders (optional fused relu(H+hbias)) ----------------
__device__ void dev_agg(int t, const int* senders_row, const int* inv,
                        const float* lgc, int edgeBase,
                        const float* Hsrc, const float* hbias, int din, float* outp,
                        int* s_row, float* s_w, float* s_scale) {
    __syncthreads();
    if (t < DEG) {
        int s = senders_row[t];
        int rr = inv ? inv[s] : s;
        s_row[t] = rr;
        s_w[t] = (edgeBase >= 0) ? lgc[edgeBase + t] : lgc[rr];
    }
    __syncthreads();
    if (t == 0) {
        float m = -1e30f;
        for (int k = 0; k < DEG; k++) m = fmaxf(m, s_w[k]);
        float d = 0.f;
        for (int k = 0; k < DEG; k++) { float v = expf(s_w[k] - m); s_w[k] = v; d += v; }
        *s_scale = 1.f / d;
    }
    __syncthreads();
    float sc = *s_scale;
    for (int c = t; c < din; c += 256) {
        float bc = hbias ? hbias[c] : 0.f;
        float a = 0.f;
#pragma unroll
        for (int k = 0; k < DEG; k++) {
            float hv = Hsrc[(size_t)s_row[k] * din + c];
            if (hbias) hv = fmaxf(hv + bc, 0.f);
            a += s_w[k] * hv;
        }
        outp[c] = a * sc;
    }
}

// ---------------- the persistent mega-kernel ----------------
__global__ __launch_bounds__(256, 2)
void k_mega(const float* __restrict__ X, const int* __restrict__ senders,
            const float* lw0, const float* lb0, const float* aw0, const float* aq0,
            const float* lw1, const float* lb1, const float* aw1, const float* aq1,
            const float* lw2, const float* lb2, const float* aw2, const float* aq2,
            const float* ow, const float* ob, float* out, WS w) {
    __shared__ char smem[17408];
    __shared__ int   s_row[DEG];
    __shared__ float s_w[DEG];
    __shared__ float s_scale;
    __shared__ int   fcnt;
    int t = threadIdx.x, bid = blockIdx.x;

    // Tree barrier: per-group arrival counter (32 RMWs/line), root (16 RMWs),
    // go-flag broadcast (32 pollers/line). The round-7/8 single-counter barrier
    // put 256-512 accesses on ONE line at the coherence point (~24 us/barrier).
    auto gsync = [&](int s) {
        __syncthreads();
        if (t == 0) {
            __threadfence();
            int g = bid >> 5;
            int* base = w.bars + s * GSTR;
            int* grp  = base + g * 16;
            int* root = base + 256;
            int* go   = base + 272 + g * 16;
            int p = __hip_atomic_fetch_add(grp, 1, __ATOMIC_RELAXED, __HIP_MEMORY_SCOPE_AGENT);
            if (p == 31) {
                int q = __hip_atomic_fetch_add(root, 1, __ATOMIC_RELAXED, __HIP_MEMORY_SCOPE_AGENT);
                if (q == NGRP - 1) {
                    for (int i = 0; i < NGRP; i++)
                        __hip_atomic_store(base + 272 + i * 16, 1, __ATOMIC_RELAXED,
                                           __HIP_MEMORY_SCOPE_AGENT);
                } else {
                    while (ld_agent(go) == 0) __builtin_amdgcn_s_sleep(4);
                }
            } else {
                while (ld_agent(go) == 0) __builtin_amdgcn_s_sleep(4);
            }
            __threadfence();
        }
        __syncthreads();
    };

    // ---- S0: block0 = frontier (levels 2,1); others = aw0 transpose->bf16 ----
    if (bid == 0) {
        unsigned* bm = (unsigned*)smem;  // 625 words
        for (int i = t; i < 625; i += 256) bm[i] = 0u;
        if (t == 0) fcnt = 0;
        __syncthreads();
        if (t < 17) {
            int node = (t < 16) ? senders[14 * DEG + t] : 14;
            unsigned bit = 1u << (node & 31);
            if (!(atomicOr(&bm[node >> 5], bit) & bit)) {
                int p = atomicAdd(&fcnt, 1); w.list2[p] = node; w.inv2[node] = p;
            }
        }
        __syncthreads();
        int c2 = fcnt;
        __syncthreads();
        for (int i = t; i < 625; i += 256) bm[i] = 0u;
        if (t == 0) { w.cnts[2] = c2; fcnt = 0; }
        __syncthreads();
        for (int i = t; i < c2 * 17; i += 256) {
            int r = i / 17, k = i - 17 * r;
            int node = (k < 16) ? senders[w.list2[r] * DEG + k] : w.list2[r];
            unsigned bit = 1u << (node & 31);
            if (!(atomicOr(&bm[node >> 5], bit) & bit)) {
                int p = atomicAdd(&fcnt, 1); w.list1[p] = node; w.inv1[node] = p;
            }
        }
        __syncthreads();
        if (t == 0) { w.cnts[1] = fcnt; w.cnts[3] = 1; w.list3[0] = 14; }
    } else {
        float* tile = (float*)smem;  // [32][33]
        for (int b = bid - 1; b < 512; b += GRID - 1) {
            __syncthreads();
            int bx = b & 15, by = b >> 4;
            int i0 = t >> 3, j0 = (t & 7) * 4;
            float4 v = *(const float4*)(aw0 + (size_t)(by * 32 + i0) * 512 + bx * 32 + j0);
            tile[i0 * 33 + j0] = v.x; tile[i0 * 33 + j0 + 1] = v.y;
            tile[i0 * 33 + j0 + 2] = v.z; tile[i0 * 33 + j0 + 3] = v.w;
            __syncthreads();
            ushort_t* p = w.awT + (size_t)(bx * 32 + i0) * 1024 + by * 32 + j0;
            p[0] = f2bf(tile[(j0 + 0) * 33 + i0]); p[1] = f2bf(tile[(j0 + 1) * 33 + i0]);
            p[2] = f2bf(tile[(j0 + 2) * 33 + i0]); p[3] = f2bf(tile[(j0 + 3) * 33 + i0]);
        }
    }
    gsync(0);

    int rc1 = ld_agent(&w.cnts[1]);
    int rc2 = ld_agent(&w.cnts[2]);
    int ne = rc1 * DEG;

    // ---- S1: gather X[sender-of-edge] -> bf16 Xg (edge-indexed, zero-padded) ----
    for (int e = bid; e < L0PAD; e += GRID) {
        unsigned lo = 0, hi = 0;
        if (e < ne) {
            int node = senders[w.list1[e >> 4] * DEG + (e & 15)];
            float4 v = *(const float4*)(X + (size_t)node * 1024 + t * 4);
            lo = (unsigned)f2bf(v.x) | ((unsigned)f2bf(v.y) << 16);
            hi = (unsigned)f2bf(v.z) | ((unsigned)f2bf(v.w) << 16);
        }
        *(uint2*)(w.Xg + (size_t)e * 1024 + t * 4) = make_uint2(lo, hi);
    }
    gsync(1);

    // ---- S2: logits0 MFMA (edge rows x aw0), 73x8 tiles ----
    for (int task = bid; task < 73 * 8; task += GRID) {
        int xr = task % 73, yc = task / 73;
        dev_logits_mfma(smem, t, w.Xg, w.awT, aq0, w.lgc0, xr * 64, yc * 64, 1024);
    }
    gsync(2);

    // ---- S3: agg layer0 -> hN0c (din=1024, Hsrc=X raw) ----
    for (int r = bid; r < rc1; r += GRID)
        dev_agg(t, senders + (size_t)w.list1[r] * DEG, nullptr, w.lgc0, r * DEG,
                X, nullptr, 1024, w.hN0c + (size_t)r * 1024, s_row, s_w, &s_scale);
    gsync(3);

    // ---- S4: h1 GEMM split-K8: C0 += concat(X[list1],hN0c) @ lw0 ----
    for (int task = bid; task < 5 * 8 * 8; task += GRID) {
        int z = task / 40, rem = task % 40, x = rem % 5, y = rem / 5;
        if (x * 64 < rc1)
            dev_mm(smem, t, X, w.hN0c, w.list1, nullptr, lw0, aq0, nullptr, w.C0, rc1,
                   1, 0, 1024, 1024, 512, x * 64, y * 64, z * 256, z * 256 + 256);
    }
    gsync(4);

    // ---- S5: logits1 (A = relu(C0+lb0) on the fly, fused relu*aq, full-K) ----
    for (int task = bid; task < 5 * 4; task += GRID) {
        int x = task % 5, y = task / 5;
        if (x * 64 < rc1)
            dev_mm(smem, t, w.C0, nullptr, nullptr, nullptr, aw1, aq1, lb0, w.lgc1, rc1,
                   0, 1, 512, 0, 256, x * 64, y * 64, 0, 512);
    }
    gsync(5);

    // ---- S6: agg layer1 -> hN1c (din=512, Hsrc = relu(C0+lb0)) ----
    for (int r = bid; r < rc2; r += GRID)
        dev_agg(t, senders + (size_t)w.list2[r] * DEG, w.inv1, w.lgc1, -1,
                w.C0, lb0, 512, w.hN1c + (size_t)r * 512, s_row, s_w, &s_scale);
    gsync(6);

    // ---- S7: h2 GEMM split-K8: C1 += concat(relu(C0+lb0)[inv1], hN1c) @ lw1 ----
    for (int task = bid; task < 4 * 8; task += GRID) {
        int y = task & 3, z = task >> 2;
        dev_mm(smem, t, w.C0, w.hN1c, w.list2, w.inv1, lw1, aq1, lb0, w.C1, rc2,
               2, 0, 512, 512, 256, 0, y * 64, z * 128, z * 128 + 128);
    }
    gsync(7);

    // ---- S8: logits2 (A = relu(C1+lb1)) ----
    for (int task = bid; task < 2; task += GRID)
        dev_mm(smem, t, w.C1, nullptr, nullptr, nullptr, aw2, aq2, lb1, w.lgc2, rc2,
               0, 1, 256, 0, 128, 0, task * 64, 0, 256);
    gsync(8);

    // ---- S9: agg layer2 (node 14 only) -> hN2c (Hsrc = relu(C1+lb1)) ----
    if (bid == 0)
        dev_agg(t, senders + 14 * DEG, w.inv2, w.lgc2, -1,
                w.C1, lb1, 256, w.hN2c, s_row, s_w, &s_scale);
    gsync(9);

    // ---- S10: h3 GEMM split-K4 -> C2 ----
    for (int task = bid; task < 2 * 4; task += GRID) {
        int y = task & 1, z = task >> 1;
        dev_mm(smem, t, w.C1, w.hN2c, w.list3, w.inv2, lw2, aq2, lb1, w.C2, 1,
               2, 0, 256, 256, 128, 0, y * 64, z * 128, z * 128 + 128);
    }
    gsync(10);

    // ---- S11: out = relu(C2+lb2) @ ow + ob ----
    if (bid == 0) {
        float* h3s = (float*)smem;
        float* part = h3s + 128;
        if (t < 128) { float v = w.C2[t] + lb2[t]; h3s[t] = v > 0.f ? v : 0.f; }
        __syncthreads();
        int j = t & 127, s = t >> 7;   // 2 k-slices of 64
        float a = 0.f;
        for (int k = s * 64; k < s * 64 + 64; k++) a += h3s[k] * ow[(size_t)k * 128 + j];
        part[s * 128 + j] = a;
        __syncthreads();
        if (t < 128) out[t] = ob[t] + part[t] + part[128 + t];
    }
}

// ---------------- launch ----------------
extern "C" void kernel_launch(void* const* d_in, const int* in_sizes, int n_in,
                              void* d_out, int out_size, void* d_ws, size_t ws_size,
                              hipStream_t stream) {
    const float* X       = (const float*)d_in[0];
    const int*   senders = (const int*)d_in[1];
    const float* lw0 = (const float*)d_in[3];
    const float* lb0 = (const float*)d_in[4];
    const float* aw0 = (const float*)d_in[5];
    const float* aq0 = (const float*)d_in[6];
    const float* lw1 = (const float*)d_in[7];
    const float* lb1 = (const float*)d_in[8];
    const float* aw1 = (const float*)d_in[9];
    const float* aq1 = (const float*)d_in[10];
    const float* lw2 = (const float*)d_in[11];
    const float* lb2 = (const float*)d_in[12];
    const float* aw2 = (const float*)d_in[13];
    const float* aq2 = (const float*)d_in[14];
    const float* owp = (const float*)d_in[15];
    const float* obp = (const float*)d_in[16];
    float* out = (float*)d_out;

    char* ws = (char*)d_ws;
    size_t off = 0;
    auto alloc = [&](size_t nbytes) -> void* {
        void* p = ws + off;
        off += (nbytes + 255) & ~(size_t)255;
        return p;
    };
    WS w;
    // ---- zero region (single hipMemsetAsync covers barriers + accumulators) ----
    w.bars = (int*)alloc(16 * GSTR * 4);     // 16 stages x tree-barrier block
    w.lgc0 = (float*)alloc(L0PAD * 4);
    w.lgc1 = (float*)alloc(MAXL1 * 4);
    w.lgc2 = (float*)alloc(MAXL2 * 4);
    w.C0   = (float*)alloc((size_t)MAXL1 * 512 * 4);
    w.C1   = (float*)alloc((size_t)MAXL2 * 256 * 4);
    w.C2   = (float*)alloc(128 * 4);
    size_t zero_end = off;
    // ---- rest ----
    w.inv1  = (int*)alloc(NN * 4);
    w.inv2  = (int*)alloc(NN * 4);
    w.list1 = (int*)alloc(MAXL1 * 4);
    w.list2 = (int*)alloc(MAXL2 * 4);
    w.list3 = (int*)alloc(4);
    w.cnts  = (int*)alloc(16);
    w.Xg    = (ushort_t*)alloc((size_t)L0PAD * 1024 * 2);
    w.awT   = (ushort_t*)alloc((size_t)512 * 1024 * 2);
    w.hN0c  = (float*)alloc((size_t)MAXL1 * 1024 * 4);
    w.hN1c  = (float*)alloc((size_t)MAXL2 * 512 * 4);
    w.hN2c  = (float*)alloc(256 * 4);
    (void)in_sizes; (void)n_in; (void)out_size; (void)ws_size;

    hipMemsetAsync(ws, 0, zero_end, stream);
    hipLaunchKernelGGL(k_mega, dim3(GRID), dim3(256), 0, stream,
                       X, senders, lw0, lb0, aw0, aq0, lw1, lb1, aw1, aq1,
                       lw2, lb2, aw2, aq2, owp, obp, out, w);
}

// Round 10
// 334.566 us; speedup vs baseline: 1.4724x; 1.4059x over previous
//
#include <hip/hip_runtime.h>
#include <math.h>

typedef unsigned short ushort_t;
typedef __attribute__((ext_vector_type(8))) short short8;
typedef __attribute__((ext_vector_type(4))) float f32x4;

// Problem constants (fixed by setup_inputs)
#define NN    20000
#define DEG   16
constexpr int MAXL2 = 1 + DEG;            // 17
constexpr int MAXL1 = MAXL2 + MAXL2*DEG;  // 289
constexpr int L0PAD = 73 * 64;            // 4672 edge rows (padded MFMA tiles)
constexpr int NWBLK = 512;                // aw0-transpose tile blocks
constexpr int TAILB = 64;                 // tail persistent blocks (1/CU, co-resident)

__device__ __forceinline__ ushort_t f2bf(float f) {
    unsigned u = __float_as_uint(f);
    return (ushort_t)((u + 0x7FFFu + ((u >> 16) & 1u)) >> 16);   // RTN-even
}
__device__ __forceinline__ int ld_agent(int* p) {
    return __hip_atomic_load(p, __ATOMIC_RELAXED, __HIP_MEMORY_SCOPE_AGENT);
}

// ---------------- frontier (block 0) + workspace zero (blocks 1..) ----------------
__global__ __launch_bounds__(256)
void k_frontier(const int* __restrict__ senders,
                int* list2, int* inv2, int* list1, int* inv1,
                int* list3, int* cnts, float4* zp, int n4) {
    int t = threadIdx.x;
    if (blockIdx.x > 0) {
        int i = (blockIdx.x - 1) * 256 + t;
        if (i < n4) zp[i] = make_float4(0.f, 0.f, 0.f, 0.f);
        return;
    }
    __shared__ unsigned bm[625];
    __shared__ int cnt;
    auto clear = [&]() { for (int i = t; i < 625; i += 256) bm[i] = 0u; if (t == 0) cnt = 0; };
    auto tryadd = [&](int node, int* list, int* inv) {
        unsigned bit = 1u << (node & 31);
        unsigned old = atomicOr(&bm[node >> 5], bit);
        if (!(old & bit)) { int p = atomicAdd(&cnt, 1); list[p] = node; inv[node] = p; }
    };
    clear(); __syncthreads();
    if (t < 17) { int node = (t < 16) ? senders[14 * DEG + t] : 14; tryadd(node, list2, inv2); }
    __syncthreads();
    int c2 = cnt; if (t == 0) cnts[2] = c2;
    __syncthreads(); clear(); __syncthreads();
    for (int i = t; i < c2 * 17; i += 256) {
        int r = i / 17, k = i - 17 * r;
        int node = (k < 16) ? senders[list2[r] * DEG + k] : list2[r];
        tryadd(node, list1, inv1);
    }
    __syncthreads();
    if (t == 0) { cnts[1] = cnt; cnts[3] = 1; list3[0] = 14; }
}

// ---------------- prep: transpose aw0 -> bf16 [N][K]  +  edge-gather X -> bf16 ----------------
__global__ __launch_bounds__(256)
void k_prep(const float* __restrict__ W, ushort_t* __restrict__ WT,
            const float* __restrict__ X, const int* __restrict__ senders,
            const int* __restrict__ list1, const int* __restrict__ cnts,
            ushort_t* __restrict__ Xg) {
    int t = threadIdx.x;
    if (blockIdx.x < NWBLK) {
        __shared__ float tile[32][33];
        int b = blockIdx.x;
        int bx = b & 15, by = b >> 4;
        int i0 = t >> 3, j0 = (t & 7) * 4;
        float4 v = *(const float4*)(W + (size_t)(by * 32 + i0) * 512 + bx * 32 + j0);
        tile[i0][j0] = v.x; tile[i0][j0 + 1] = v.y; tile[i0][j0 + 2] = v.z; tile[i0][j0 + 3] = v.w;
        __syncthreads();
        ushort_t* p = WT + (size_t)(bx * 32 + i0) * 1024 + by * 32 + j0;
        p[0] = f2bf(tile[j0 + 0][i0]); p[1] = f2bf(tile[j0 + 1][i0]);
        p[2] = f2bf(tile[j0 + 2][i0]); p[3] = f2bf(tile[j0 + 3][i0]);
    } else {
        int e = blockIdx.x - NWBLK;
        int ne = cnts[1] * DEG;
        unsigned lo = 0, hi = 0;
        if (e < ne) {
            int node = senders[list1[e >> 4] * DEG + (e & 15)];
            float4 v = *(const float4*)(X + (size_t)node * 1024 + t * 4);
            lo = (unsigned)f2bf(v.x) | ((unsigned)f2bf(v.y) << 16);
            hi = (unsigned)f2bf(v.z) | ((unsigned)f2bf(v.w) << 16);
        }
        *(uint2*)(Xg + (size_t)e * 1024 + t * 4) = make_uint2(lo, hi);
    }
}

// ---------------- bf16 MFMA logits GEMM (edge rows), grid (73, 8) ----------------
__global__ __launch_bounds__(256)
void k_logits_mfma(const ushort_t* __restrict__ Xg, const ushort_t* __restrict__ WT,
                   const float* __restrict__ aq, float* __restrict__ lgc) {
    __shared__ short As[64 * 40];
    __shared__ short Bs[64 * 40];
    const int K = 1024;
    int row0 = blockIdx.x * 64, col0 = blockIdx.y * 64;
    int t = threadIdx.x;
    int w = t >> 6, lane = t & 63;
    int sr = t >> 2, sk = (t & 3) * 8;
    const ushort_t* ap = Xg + (size_t)(row0 + sr) * K + sk;
    const ushort_t* bp = WT + (size_t)(col0 + sr) * K + sk;
    int fm = lane & 15, fq = lane >> 4;
    const short* arow = As + (w * 16 + fm) * 40 + fq * 8;
    const short* brow = Bs + fm * 40 + fq * 8;

    f32x4 acc0 = {0.f,0.f,0.f,0.f}, acc1 = {0.f,0.f,0.f,0.f};
    f32x4 acc2 = {0.f,0.f,0.f,0.f}, acc3 = {0.f,0.f,0.f,0.f};

    short8 pa = *(const short8*)(ap);
    short8 pb = *(const short8*)(bp);
    for (int k0 = 0; k0 < K; k0 += 32) {
        *(short8*)(As + sr * 40 + sk) = pa;
        *(short8*)(Bs + sr * 40 + sk) = pb;
        __syncthreads();
        if (k0 + 32 < K) {
            pa = *(const short8*)(ap + k0 + 32);
            pb = *(const short8*)(bp + k0 + 32);
        }
        short8 af = *(const short8*)arow;
        short8 b0 = *(const short8*)(brow);
        short8 b1 = *(const short8*)(brow + 16 * 40);
        short8 b2 = *(const short8*)(brow + 32 * 40);
        short8 b3 = *(const short8*)(brow + 48 * 40);
        acc0 = __builtin_amdgcn_mfma_f32_16x16x32_bf16(af, b0, acc0, 0, 0, 0);
        acc1 = __builtin_amdgcn_mfma_f32_16x16x32_bf16(af, b1, acc1, 0, 0, 0);
        acc2 = __builtin_amdgcn_mfma_f32_16x16x32_bf16(af, b2, acc2, 0, 0, 0);
        acc3 = __builtin_amdgcn_mfma_f32_16x16x32_bf16(af, b3, acc3, 0, 0, 0);
        __syncthreads();
    }
    float aqv0 = aq[col0 + fm], aqv1 = aq[col0 + 16 + fm];
    float aqv2 = aq[col0 + 32 + fm], aqv3 = aq[col0 + 48 + fm];
#pragma unroll
    for (int r = 0; r < 4; r++) {
        float v = fmaxf(acc0[r], 0.f) * aqv0 + fmaxf(acc1[r], 0.f) * aqv1
                + fmaxf(acc2[r], 0.f) * aqv2 + fmaxf(acc3[r], 0.f) * aqv3;
#pragma unroll
        for (int off = 1; off < 16; off <<= 1) v += __shfl_xor(v, off);
        if (fm == 0) atomicAdd(&lgc[row0 + w * 16 + fq * 4 + r], v);
    }
}

// ---------------- softmax-aggregate core ----------------
__device__ void dev_agg(int t, const int* senders_row, const int* inv,
                        const float* lgc, int edgeBase,
                        const float* Hsrc, const float* hbias, int din, float* outp,
                        int* s_row, float* s_w, float* s_scale) {
    __syncthreads();
    if (t < DEG) {
        int s = senders_row[t];
        int rr = inv ? inv[s] : s;
        s_row[t] = rr;
        s_w[t] = (edgeBase >= 0) ? lgc[edgeBase + t] : lgc[rr];
    }
    __syncthreads();
    if (t == 0) {
        float m = -1e30f;
        for (int k = 0; k < DEG; k++) m = fmaxf(m, s_w[k]);
        float d = 0.f;
        for (int k = 0; k < DEG; k++) { float v = expf(s_w[k] - m); s_w[k] = v; d += v; }
        *s_scale = 1.f / d;
    }
    __syncthreads();
    float sc = *s_scale;
    for (int c = t; c < din; c += 256) {
        float bc = hbias ? hbias[c] : 0.f;
        float a = 0.f;
#pragma unroll
        for (int k = 0; k < DEG; k++) {
            float hv = Hsrc[(size_t)s_row[k] * din + c];
            if (hbias) hv = fmaxf(hv + bc, 0.f);
            a += s_w[k] * hv;
        }
        outp[c] = a * sc;
    }
}

// ---------------- layer-0 aggregate kernel (grid MAXL1) ----------------
__global__ __launch_bounds__(256)
void k_agg0(const float* __restrict__ X, const int* __restrict__ senders,
            const float* __restrict__ lgc0, const int* __restrict__ list1,
            const int* __restrict__ cnts, float* __restrict__ hN0c) {
    __shared__ int   s_row[DEG];
    __shared__ float s_w[DEG];
    __shared__ float s_scale;
    int b = blockIdx.x;
    if (b >= cnts[1]) return;
    dev_agg(threadIdx.x, senders + (size_t)list1[b] * DEG, nullptr, lgc0, b * DEG,
            X, nullptr, 1024, hN0c + (size_t)b * 1024, s_row, s_w, &s_scale);
}

// ---------------- fp32 tile GEMM core (64x64, BK=32, register-prefetch) ----------------
// A1 rows get optional fused relu(x+abias). omode 0: C += acc (atomic, split-K OK).
// omode 1: lgc[r] += sum relu(acc)*aq (NO split-K).
__device__ void dev_mm(char* smem, int t,
                       const float* A1, const float* A2, const int* list, const int* inv,
                       const float* B, const float* aq, const float* abias,
                       float* C, int rcnt,
                       int amode, int omode, int K1, int K2, int NC,
                       int row0, int col0, int kbeg, int kend) {
    float* As = (float*)smem;              // [32][68]
    float* Bs = As + 32 * 68;              // [32][64]
    float* rowsum = (float*)(smem + 16896);
    __syncthreads();

    int ty = t >> 4, tx = t & 15;
    int lr = t >> 2, kaoff = (t & 3) * 4;
    int grow = row0 + lr;
    bool rowValid = grow < rcnt;
    const float* rp1 = A1;
    const float* rp2 = A2;
    if (rowValid) {
        int hrow;
        if (amode == 0) hrow = grow;
        else { int node = list[grow]; hrow = (amode == 2) ? inv[node] : node; }
        rp1 = A1 + (size_t)hrow * K1;
        rp2 = A2 + (size_t)grow * K2;
    }
    const float* Bp = B + col0;
    int bidx0 = t, bidx1 = t + 256;

    auto loadA = [&](int k) -> float4 {
        if (!rowValid) return make_float4(0.f, 0.f, 0.f, 0.f);
        if (k < K1) {
            float4 v = *(const float4*)(rp1 + k);
            if (abias) {
                const float4 b = *(const float4*)(abias + k);
                v.x = fmaxf(v.x + b.x, 0.f); v.y = fmaxf(v.y + b.y, 0.f);
                v.z = fmaxf(v.z + b.z, 0.f); v.w = fmaxf(v.w + b.w, 0.f);
            }
            return v;
        }
        return *(const float4*)(rp2 + (k - K1));
    };
    auto loadB = [&](int idx, int k0) -> float4 {
        int row = idx >> 4, c4 = (idx & 15) * 4;
        return *(const float4*)(Bp + (size_t)(k0 + row) * NC + c4);
    };

    float4 pa0 = loadA(kbeg + kaoff);
    float4 pa1 = loadA(kbeg + kaoff + 16);
    float4 pb0 = loadB(bidx0, kbeg);
    float4 pb1 = loadB(bidx1, kbeg);

    float acc[4][4] = {};
    for (int k0 = kbeg; k0 < kend; k0 += 32) {
        As[(kaoff + 0) * 68 + lr] = pa0.x; As[(kaoff + 1) * 68 + lr] = pa0.y;
        As[(kaoff + 2) * 68 + lr] = pa0.z; As[(kaoff + 3) * 68 + lr] = pa0.w;
        As[(kaoff + 16) * 68 + lr] = pa1.x; As[(kaoff + 17) * 68 + lr] = pa1.y;
        As[(kaoff + 18) * 68 + lr] = pa1.z; As[(kaoff + 19) * 68 + lr] = pa1.w;
        *(float4*)&Bs[(bidx0 >> 4) * 64 + (bidx0 & 15) * 4] = pb0;
        *(float4*)&Bs[(bidx1 >> 4) * 64 + (bidx1 & 15) * 4] = pb1;
        __syncthreads();
        if (k0 + 32 < kend) {
            pa0 = loadA(k0 + 32 + kaoff);
            pa1 = loadA(k0 + 32 + kaoff + 16);
            pb0 = loadB(bidx0, k0 + 32);
            pb1 = loadB(bidx1, k0 + 32);
        }
#pragma unroll
        for (int kk = 0; kk < 32; kk++) {
            float4 a4 = *(const float4*)&As[kk * 68 + ty * 4];
            float4 b4 = *(const float4*)&Bs[kk * 64 + tx * 4];
            float a[4] = {a4.x, a4.y, a4.z, a4.w};
            float b[4] = {b4.x, b4.y, b4.z, b4.w};
#pragma unroll
            for (int i = 0; i < 4; i++)
#pragma unroll
                for (int j = 0; j < 4; j++) acc[i][j] += a[i] * b[j];
        }
        __syncthreads();
    }

    if (omode == 0) {
#pragma unroll
        for (int i = 0; i < 4; i++) {
            int r = row0 + ty * 4 + i;
            if (r < rcnt) {
                float* Crow = C + (size_t)r * NC + col0 + tx * 4;
#pragma unroll
                for (int j = 0; j < 4; j++) atomicAdd(&Crow[j], acc[i][j]);
            }
        }
    } else {
        if (t < 64) rowsum[t] = 0.f;
        __syncthreads();
        float aqv[4];
#pragma unroll
        for (int j = 0; j < 4; j++) aqv[j] = aq[col0 + tx * 4 + j];
#pragma unroll
        for (int i = 0; i < 4; i++) {
            float s = 0.f;
#pragma unroll
            for (int j = 0; j < 4; j++) {
                float v = acc[i][j];
                v = v > 0.f ? v : 0.f;
                s += v * aqv[j];
            }
            atomicAdd(&rowsum[ty * 4 + i], s);
        }
        __syncthreads();
        if (t < 64) {
            int r = row0 + t;
            if (r < rcnt) atomicAdd(&C[r], rowsum[t]);
        }
    }
}

// ---------------- h1 GEMM kernel: grid (5, 8, 8) ----------------
__global__ __launch_bounds__(256)
void k_h1(const float* __restrict__ X, const float* __restrict__ hN0c,
          const int* __restrict__ list1, const int* __restrict__ cnts,
          const float* __restrict__ lw0, float* __restrict__ C0) {
    __shared__ char smem[17408];
    int rcnt = cnts[1];
    int row0 = blockIdx.x * 64;
    if (row0 >= rcnt) return;
    dev_mm(smem, threadIdx.x, X, hN0c, list1, nullptr, lw0, nullptr, nullptr, C0, rcnt,
           1, 0, 1024, 1024, 512, row0, blockIdx.y * 64,
           blockIdx.z * 256, blockIdx.z * 256 + 256);
}

// ---------------- persistent tail: layers 1-2 + out, 64 blocks, 6 barriers ----------------
__global__ __launch_bounds__(256, 2)
void k_tail(const float* __restrict__ senders_f, const int* __restrict__ senders,
            const float* lb0, const float* aw1, const float* aq1,
            const float* lw1, const float* lb1, const float* aw2, const float* aq2,
            const float* lw2, const float* lb2, const float* ow, const float* ob,
            float* out, int* bars, const int* cnts,
            const int* list2, const int* inv1, const int* inv2, const int* list3,
            const float* C0, float* lgc1, float* hN1c, float* C1,
            float* lgc2, float* hN2c, float* C2) {
    __shared__ char smem[17408];
    __shared__ int   s_row[DEG];
    __shared__ float s_w[DEG];
    __shared__ float s_scale;
    int t = threadIdx.x, bid = blockIdx.x;
    (void)senders_f;

    auto bar = [&](int i) {
        __syncthreads();
        if (t == 0) {
            __threadfence();
            atomicAdd(&bars[i * 16], 1);
            while (ld_agent(&bars[i * 16]) < TAILB) __builtin_amdgcn_s_sleep(2);
            __threadfence();
        }
        __syncthreads();
    };

    int rc1 = cnts[1], rc2 = cnts[2];

    // T0: logits1 — A = relu(C0+lb0), fused relu*aq, full-K (20 tasks)
    for (int task = bid; task < 5 * 4; task += TAILB) {
        int x = task % 5, y = task / 5;
        if (x * 64 < rc1)
            dev_mm(smem, t, C0, nullptr, nullptr, nullptr, aw1, aq1, lb0, lgc1, rc1,
                   0, 1, 512, 0, 256, x * 64, y * 64, 0, 512);
    }
    bar(0);

    // T1: agg1 -> hN1c (17 blocks)
    for (int r = bid; r < rc2; r += TAILB)
        dev_agg(t, senders + (size_t)list2[r] * DEG, inv1, lgc1, -1,
                C0, lb0, 512, hN1c + (size_t)r * 512, s_row, s_w, &s_scale);
    bar(1);

    // T2: h2 split-K4 (16 tasks)
    for (int task = bid; task < 4 * 4; task += TAILB) {
        int y = task & 3, z = task >> 2;
        dev_mm(smem, t, C0, hN1c, list2, inv1, lw1, nullptr, lb0, C1, rc2,
               2, 0, 512, 512, 256, 0, y * 64, z * 256, z * 256 + 256);
    }
    bar(2);

    // T3: logits2 (2 tasks)
    for (int task = bid; task < 2; task += TAILB)
        dev_mm(smem, t, C1, nullptr, nullptr, nullptr, aw2, aq2, lb1, lgc2, rc2,
               0, 1, 256, 0, 128, 0, task * 64, 0, 256);
    bar(3);

    // T4: agg2 (node 14) -> hN2c
    if (bid == 0)
        dev_agg(t, senders + 14 * DEG, inv2, lgc2, -1,
                C1, lb1, 256, hN2c, s_row, s_w, &s_scale);
    bar(4);

    // T5: h3 split-K2 (4 tasks)
    for (int task = bid; task < 2 * 2; task += TAILB) {
        int y = task & 1, z = task >> 1;
        dev_mm(smem, t, C1, hN2c, list3, inv2, lw2, nullptr, lb1, C2, 1,
               2, 0, 256, 256, 128, 0, y * 64, z * 256, z * 256 + 256);
    }
    bar(5);

    // T6: out = relu(C2+lb2) @ ow + ob
    if (bid == 0) {
        float* h3s = (float*)smem;
        float* part = h3s + 128;
        if (t < 128) { float v = C2[t] + lb2[t]; h3s[t] = v > 0.f ? v : 0.f; }
        __syncthreads();
        int j = t & 127, s = t >> 7;
        float a = 0.f;
        for (int k = s * 64; k < s * 64 + 64; k++) a += h3s[k] * ow[(size_t)k * 128 + j];
        part[s * 128 + j] = a;
        __syncthreads();
        if (t < 128) out[t] = ob[t] + part[t] + part[128 + t];
    }
}

// ---------------- launch ----------------
extern "C" void kernel_launch(void* const* d_in, const int* in_sizes, int n_in,
                              void* d_out, int out_size, void* d_ws, size_t ws_size,
                              hipStream_t stream) {
    const float* X       = (const float*)d_in[0];
    const int*   senders = (const int*)d_in[1];
    const float* lw0 = (const float*)d_in[3];
    const float* lb0 = (const float*)d_in[4];
    const float* aw0 = (const float*)d_in[5];
    const float* aq0 = (const float*)d_in[6];
    const float* lw1 = (const float*)d_in[7];
    const float* lb1 = (const float*)d_in[8];
    const float* aw1 = (const float*)d_in[9];
    const float* aq1 = (const float*)d_in[10];
    const float* lw2 = (const float*)d_in[11];
    const float* lb2 = (const float*)d_in[12];
    const float* aw2 = (const float*)d_in[13];
    const float* aq2 = (const float*)d_in[14];
    const float* owp = (const float*)d_in[15];
    const float* obp = (const float*)d_in[16];
    float* out = (float*)d_out;

    char* ws = (char*)d_ws;
    size_t off = 0;
    auto alloc = [&](size_t nbytes) -> void* {
        void* p = ws + off;
        off += (nbytes + 255) & ~(size_t)255;
        return p;
    };
    // ---- zero region (k_frontier's extra blocks zero this) ----
    int*   bars = (int*)alloc(6 * 16 * 4);   // one counter per 64B line
    float* lgc0 = (float*)alloc(L0PAD * 4);
    float* lgc1 = (float*)alloc(MAXL1 * 4);
    float* lgc2 = (float*)alloc(MAXL2 * 4);
    float* C0   = (float*)alloc((size_t)MAXL1 * 512 * 4);
    float* C1   = (float*)alloc((size_t)MAXL2 * 256 * 4);
    float* C2   = (float*)alloc(128 * 4);
    size_t zero_end = off;
    // ---- rest ----
    int* inv1  = (int*)alloc(NN * 4);
    int* inv2  = (int*)alloc(NN * 4);
    int* list1 = (int*)alloc(MAXL1 * 4);
    int* list2 = (int*)alloc(MAXL2 * 4);
    int* list3 = (int*)alloc(4);
    int* cnts  = (int*)alloc(16);
    ushort_t* Xg  = (ushort_t*)alloc((size_t)L0PAD * 1024 * 2);
    ushort_t* awT = (ushort_t*)alloc((size_t)512 * 1024 * 2);
    float* hN0c = (float*)alloc((size_t)MAXL1 * 1024 * 4);
    float* hN1c = (float*)alloc((size_t)MAXL2 * 512 * 4);
    float* hN2c = (float*)alloc(256 * 4);
    (void)in_sizes; (void)n_in; (void)out_size; (void)ws_size;

    int nz4 = (int)(zero_end / 16);
    int nzb = (nz4 + 255) / 256;

    hipLaunchKernelGGL(k_frontier, dim3(1 + nzb), dim3(256), 0, stream,
                       senders, list2, inv2, list1, inv1, list3, cnts, (float4*)ws, nz4);
    hipLaunchKernelGGL(k_prep, dim3(NWBLK + L0PAD), dim3(256), 0, stream,
                       aw0, awT, X, senders, list1, cnts, Xg);
    hipLaunchKernelGGL(k_logits_mfma, dim3(73, 8), dim3(256), 0, stream,
                       Xg, awT, aq0, lgc0);
    hipLaunchKernelGGL(k_agg0, dim3(MAXL1), dim3(256), 0, stream,
                       X, senders, lgc0, list1, cnts, hN0c);
    hipLaunchKernelGGL(k_h1, dim3(5, 8, 8), dim3(256), 0, stream,
                       X, hN0c, list1, cnts, lw0, C0);
    hipLaunchKernelGGL(k_tail, dim3(TAILB), dim3(256), 0, stream,
                       X, senders, lb0, aw1, aq1, lw1, lb1, aw2, aq2,
                       lw2, lb2, owp, obp, out, bars, cnts,
                       list2, inv1, inv2, list3,
                       C0, lgc1, hN1c, C1, lgc2, hN2c, C2);
}